// Round 1
// baseline (1430.551 us; speedup 1.0000x reference)
//
#include <hip/hip_runtime.h>

#define NB 2
#define NS 2048
#define NDM 768
#define NH 12
#define ND 64
// dist_emb rows = 2*NS - 1 = 4095

// ---------------------------------------------------------------- QKV GEMM
// C = X @ W + bias;  X [4096 x 768] row-major, W [768 x 768] row-major.
// Output written directly in [B, H, S, D] layout.
// BM=BN=128, BK=16, 256 threads, 8x8 per thread.
__launch_bounds__(256)
__global__ void qkv_gemm(const float* __restrict__ X,
                         const float* __restrict__ W,
                         const float* __restrict__ bias,
                         float* __restrict__ dst) {
  __shared__ float Xs[16][128];   // [k][m] transposed for b128 reads along m
  __shared__ float Ws[16][132];   // [k][n], +4 pad to break write conflicts

  const int t  = threadIdx.x;
  const int tx = t & 15;   // n-group (8 cols each)
  const int ty = t >> 4;   // m-group (8 rows each)
  const int m0 = blockIdx.y * 128;
  const int n0 = blockIdx.x * 128;

  float acc[8][8];
#pragma unroll
  for (int i = 0; i < 8; ++i)
#pragma unroll
    for (int j = 0; j < 8; ++j) acc[i][j] = 0.f;

  const int xr = t & 127;  // X staging: row
  const int xc = t >> 7;   // 0..1
  const int wr = t & 15;   // W staging: row
  const int wc = t >> 4;   // 0..15

  for (int kt = 0; kt < NDM / 16; ++kt) {
#pragma unroll
    for (int j = 0; j < 2; ++j) {
      const int c4 = xc * 2 + j;  // 0..3
      const float4 vx = *reinterpret_cast<const float4*>(
          &X[(size_t)(m0 + xr) * NDM + kt * 16 + c4 * 4]);
      Xs[c4 * 4 + 0][xr] = vx.x;
      Xs[c4 * 4 + 1][xr] = vx.y;
      Xs[c4 * 4 + 2][xr] = vx.z;
      Xs[c4 * 4 + 3][xr] = vx.w;
    }
#pragma unroll
    for (int j = 0; j < 2; ++j) {
      const int c4 = wc + 16 * j;  // 0..31
      const float4 vw = *reinterpret_cast<const float4*>(
          &W[(size_t)(kt * 16 + wr) * NDM + n0 + c4 * 4]);
      *reinterpret_cast<float4*>(&Ws[wr][c4 * 4]) = vw;
    }
    __syncthreads();
#pragma unroll
    for (int kk = 0; kk < 16; ++kk) {
      float a[8], bb[8];
      *reinterpret_cast<float4*>(&a[0]) =
          *reinterpret_cast<const float4*>(&Xs[kk][ty * 8]);
      *reinterpret_cast<float4*>(&a[4]) =
          *reinterpret_cast<const float4*>(&Xs[kk][ty * 8 + 4]);
      *reinterpret_cast<float4*>(&bb[0]) =
          *reinterpret_cast<const float4*>(&Ws[kk][tx * 8]);
      *reinterpret_cast<float4*>(&bb[4]) =
          *reinterpret_cast<const float4*>(&Ws[kk][tx * 8 + 4]);
#pragma unroll
      for (int i = 0; i < 8; ++i)
#pragma unroll
        for (int j = 0; j < 8; ++j)
          acc[i][j] = fmaf(a[i], bb[j], acc[i][j]);
    }
    __syncthreads();
  }

#pragma unroll
  for (int i = 0; i < 8; ++i) {
    const int m  = m0 + ty * 8 + i;
    const int bb_ = m >> 11;        // / 2048
    const int ss  = m & (NS - 1);
#pragma unroll
    for (int j4 = 0; j4 < 2; ++j4) {
      const int n  = n0 + tx * 8 + j4 * 4;
      const int hh = n >> 6;
      const int dd = n & (ND - 1);
      const float4 bv4 = *reinterpret_cast<const float4*>(&bias[n]);
      float4 o;
      o.x = acc[i][j4 * 4 + 0] + bv4.x;
      o.y = acc[i][j4 * 4 + 1] + bv4.y;
      o.z = acc[i][j4 * 4 + 2] + bv4.z;
      o.w = acc[i][j4 * 4 + 3] + bv4.w;
      *reinterpret_cast<float4*>(
          &dst[(((size_t)bb_ * NH + hh) * NS + ss) * ND + dd]) = o;
    }
  }
}

// ---------------------------------------------------------------- attention
// Flash-style, fp32. 1 wg per (bh, 64-row query block). 256 threads.
// scores[l][r] = q_l.k_r + (q_l + k_r).E_{l-r+2047}; /8; +mask; softmax; @V.
__launch_bounds__(256)
__global__ void attn_kernel(const float* __restrict__ q,   // [B,H,S,D]
                            const float* __restrict__ k,   // [B,H,S,D]
                            const float* __restrict__ v,   // [B,H,S,D]
                            const float* __restrict__ E,   // [4095, 64]
                            const float* __restrict__ mask,// [B*S]
                            float* __restrict__ out) {     // [B,S,DM]
  __shared__ float Qs[ND][64];       // [i][l]   16 KB (transposed)
  __shared__ float Ks[ND][64];       // [i][r]   16 KB (transposed)
  __shared__ float Vs[64][ND + 4];   // [r][i]   17 KB
  __shared__ float Es[ND][128];      // [i][dloc] 32 KB (transposed, dloc 0..126)
  __shared__ float Ps[64][64 + 4];   // [r][l]   17 KB

  const int t  = threadIdx.x;
  const int tx = t & 15;   // r-group / d-group (4 each)
  const int ty = t >> 4;   // l-group (4 each)
  const int l0 = blockIdx.x * 64;
  const int bh = blockIdx.y;
  const int b  = bh / NH;
  const int h  = bh % NH;

  const float* qp = q + ((size_t)bh * NS + l0) * ND;
  const float* kp = k + (size_t)bh * NS * ND;
  const float* vp = v + (size_t)bh * NS * ND;

  // stage Q transposed (once)
  {
    const int rr = t & 63;
    const int w  = t >> 6;
#pragma unroll
    for (int j = 0; j < 4; ++j) {
      const int c = w * 4 + j;
      const float4 val =
          *reinterpret_cast<const float4*>(&qp[(size_t)rr * ND + c * 4]);
      Qs[c * 4 + 0][rr] = val.x;
      Qs[c * 4 + 1][rr] = val.y;
      Qs[c * 4 + 2][rr] = val.z;
      Qs[c * 4 + 3][rr] = val.w;
    }
  }

  float O[4][4];
  float m_run[4], l_run[4];
#pragma unroll
  for (int i = 0; i < 4; ++i) {
    m_run[i] = -1e30f;
    l_run[i] = 0.f;
#pragma unroll
    for (int j = 0; j < 4; ++j) O[i][j] = 0.f;
  }

  for (int r0 = 0; r0 < NS; r0 += 64) {
    __syncthreads();  // prev-iter PV done before restage
    // stage K (transposed) and V (row-major)
    {
      const int rr = t & 63;
      const int w  = t >> 6;
#pragma unroll
      for (int j = 0; j < 4; ++j) {
        const int c = w * 4 + j;
        const float4 kv4 = *reinterpret_cast<const float4*>(
            &kp[(size_t)(r0 + rr) * ND + c * 4]);
        Ks[c * 4 + 0][rr] = kv4.x;
        Ks[c * 4 + 1][rr] = kv4.y;
        Ks[c * 4 + 2][rr] = kv4.z;
        Ks[c * 4 + 3][rr] = kv4.w;
        const float4 vv4 = *reinterpret_cast<const float4*>(
            &vp[(size_t)(r0 + rr) * ND + c * 4]);
        *reinterpret_cast<float4*>(&Vs[rr][c * 4]) = vv4;
      }
    }
    // stage E slice (transposed): d_global = (l0-r0+2047) - 63 + dloc, dloc 0..126
    {
      const int dloc = t >> 1;
      const int half = t & 1;
      if (dloc < 127) {
        const float* ep =
            E + (size_t)(l0 - r0 + (NS - 1) - 63 + dloc) * ND + half * 32;
#pragma unroll
        for (int j = 0; j < 8; ++j) {
          const float4 val = *reinterpret_cast<const float4*>(&ep[j * 4]);
          const int i = half * 32 + j * 4;
          Es[i + 0][dloc] = val.x;
          Es[i + 1][dloc] = val.y;
          Es[i + 2][dloc] = val.z;
          Es[i + 3][dloc] = val.w;
        }
      }
    }
    __syncthreads();

    // ---- scores: 4l x 4r per thread
    float sc[4][4];
#pragma unroll
    for (int a = 0; a < 4; ++a)
#pragma unroll
      for (int c = 0; c < 4; ++c) sc[a][c] = 0.f;

    const int eb = (ty - tx) * 4 + 60;  // aligned base; needed dloc = eb+3+jl-jr
#pragma unroll 4
    for (int i = 0; i < ND; ++i) {
      float qv[4], kv[4], ev[8];
      *reinterpret_cast<float4*>(&qv[0]) =
          *reinterpret_cast<const float4*>(&Qs[i][ty * 4]);
      *reinterpret_cast<float4*>(&kv[0]) =
          *reinterpret_cast<const float4*>(&Ks[i][tx * 4]);
      *reinterpret_cast<float4*>(&ev[0]) =
          *reinterpret_cast<const float4*>(&Es[i][eb]);
      *reinterpret_cast<float4*>(&ev[4]) =
          *reinterpret_cast<const float4*>(&Es[i][eb + 4]);
#pragma unroll
      for (int jl = 0; jl < 4; ++jl)
#pragma unroll
        for (int jr = 0; jr < 4; ++jr) {
          sc[jl][jr] = fmaf(qv[jl], kv[jr], sc[jl][jr]);
          sc[jl][jr] = fmaf(qv[jl] + kv[jr], ev[3 + jl - jr], sc[jl][jr]);
        }
    }

    // ---- online softmax
    float mk[4];
    {
      const float4 m4 = *reinterpret_cast<const float4*>(
          &mask[(size_t)b * NS + r0 + tx * 4]);
      mk[0] = m4.x; mk[1] = m4.y; mk[2] = m4.z; mk[3] = m4.w;
    }
    float mrow[4];
#pragma unroll
    for (int jl = 0; jl < 4; ++jl) {
      float mx = -1e30f;
#pragma unroll
      for (int jr = 0; jr < 4; ++jr) {
        const float val = sc[jl][jr] * 0.125f + mk[jr];
        sc[jl][jr] = val;
        mx = fmaxf(mx, val);
      }
      mrow[jl] = mx;
    }
#pragma unroll
    for (int off = 1; off < 16; off <<= 1)
#pragma unroll
      for (int jl = 0; jl < 4; ++jl)
        mrow[jl] = fmaxf(mrow[jl], __shfl_xor(mrow[jl], off));

    float pr[4][4], alpha[4], psum[4];
#pragma unroll
    for (int jl = 0; jl < 4; ++jl) {
      const float mnew = fmaxf(m_run[jl], mrow[jl]);
      alpha[jl] = __expf(m_run[jl] - mnew);
      m_run[jl] = mnew;
      float ps = 0.f;
#pragma unroll
      for (int jr = 0; jr < 4; ++jr) {
        const float p = __expf(sc[jl][jr] - mnew);
        pr[jl][jr] = p;
        ps += p;
      }
      psum[jl] = ps;
    }
#pragma unroll
    for (int off = 1; off < 16; off <<= 1)
#pragma unroll
      for (int jl = 0; jl < 4; ++jl) psum[jl] += __shfl_xor(psum[jl], off);
#pragma unroll
    for (int jl = 0; jl < 4; ++jl) {
      l_run[jl] = l_run[jl] * alpha[jl] + psum[jl];
#pragma unroll
      for (int jd = 0; jd < 4; ++jd) O[jl][jd] *= alpha[jl];
    }
    // write P transposed: Ps[r][l], float4 along l
#pragma unroll
    for (int jr = 0; jr < 4; ++jr) {
      float4 p4;
      p4.x = pr[0][jr]; p4.y = pr[1][jr]; p4.z = pr[2][jr]; p4.w = pr[3][jr];
      *reinterpret_cast<float4*>(&Ps[tx * 4 + jr][ty * 4]) = p4;
    }
    __syncthreads();

    // ---- PV: O[l][d] += sum_r P[r][l] * V[r][d]
#pragma unroll 4
    for (int rr = 0; rr < 64; ++rr) {
      const float4 p4 = *reinterpret_cast<const float4*>(&Ps[rr][ty * 4]);
      const float4 v4 = *reinterpret_cast<const float4*>(&Vs[rr][tx * 4]);
      const float pa[4] = {p4.x, p4.y, p4.z, p4.w};
      const float va[4] = {v4.x, v4.y, v4.z, v4.w};
#pragma unroll
      for (int jl = 0; jl < 4; ++jl)
#pragma unroll
        for (int jd = 0; jd < 4; ++jd)
          O[jl][jd] = fmaf(pa[jl], va[jd], O[jl][jd]);
    }
  }

  // epilogue: normalize and store [B,S,DM]
#pragma unroll
  for (int jl = 0; jl < 4; ++jl) {
    const float inv = 1.0f / l_run[jl];
    const int l = l0 + ty * 4 + jl;
    float4 o;
    o.x = O[jl][0] * inv;
    o.y = O[jl][1] * inv;
    o.z = O[jl][2] * inv;
    o.w = O[jl][3] * inv;
    *reinterpret_cast<float4*>(
        &out[((size_t)b * NS + l) * NDM + h * ND + tx * 4]) = o;
  }
}

extern "C" void kernel_launch(void* const* d_in, const int* in_sizes, int n_in,
                              void* d_out, int out_size, void* d_ws, size_t ws_size,
                              hipStream_t stream) {
  const float* hs  = (const float*)d_in[0];
  const float* msk = (const float*)d_in[1];
  const float* Wq  = (const float*)d_in[2];
  const float* bq  = (const float*)d_in[3];
  const float* Wk  = (const float*)d_in[4];
  const float* bk  = (const float*)d_in[5];
  const float* Wv  = (const float*)d_in[6];
  const float* bv  = (const float*)d_in[7];
  const float* Ept = (const float*)d_in[8];
  float* out = (float*)d_out;

  const size_t per = (size_t)NB * NH * NS * ND;  // 3,145,728 floats
  float* qb = (float*)d_ws;
  float* kb = qb + per;
  float* vb = kb + per;

  dim3 gg(NDM / 128, (NB * NS) / 128);  // (6, 32)
  qkv_gemm<<<gg, 256, 0, stream>>>(hs, Wq, bq, qb);
  qkv_gemm<<<gg, 256, 0, stream>>>(hs, Wk, bk, kb);
  qkv_gemm<<<gg, 256, 0, stream>>>(hs, Wv, bv, vb);

  attn_kernel<<<dim3(NS / 64, NB * NH), 256, 0, stream>>>(qb, kb, vb, Ept,
                                                          msk, out);
}

// Round 2
// 1248.857 us; speedup vs baseline: 1.1455x; 1.1455x over previous
//
#include <hip/hip_runtime.h>
#include <hip/hip_fp16.h>

#define NB 2
#define NS 2048
#define NDM 768
#define NH 12
#define ND 64
// dist_emb rows = 2*NS - 1 = 4095

// ---------------------------------------------------------------- QKV GEMM
// C = X @ W + bias;  X [4096 x 768] row-major, W [768 x 768] row-major.
// Output written directly in [B, H, S, D] layout.
// BM=BN=128, BK=16, 256 threads, 8x8 per thread.
__launch_bounds__(256)
__global__ void qkv_gemm(const float* __restrict__ X,
                         const float* __restrict__ W,
                         const float* __restrict__ bias,
                         float* __restrict__ dst) {
  __shared__ float Xs[16][128];   // [k][m] transposed for b128 reads along m
  __shared__ float Ws[16][132];   // [k][n], +4 pad to break write conflicts

  const int t  = threadIdx.x;
  const int tx = t & 15;   // n-group (8 cols each)
  const int ty = t >> 4;   // m-group (8 rows each)
  const int m0 = blockIdx.y * 128;
  const int n0 = blockIdx.x * 128;

  float acc[8][8];
#pragma unroll
  for (int i = 0; i < 8; ++i)
#pragma unroll
    for (int j = 0; j < 8; ++j) acc[i][j] = 0.f;

  const int xr = t & 127;  // X staging: row
  const int xc = t >> 7;   // 0..1
  const int wr = t & 15;   // W staging: row
  const int wc = t >> 4;   // 0..15

  for (int kt = 0; kt < NDM / 16; ++kt) {
#pragma unroll
    for (int j = 0; j < 2; ++j) {
      const int c4 = xc * 2 + j;  // 0..3
      const float4 vx = *reinterpret_cast<const float4*>(
          &X[(size_t)(m0 + xr) * NDM + kt * 16 + c4 * 4]);
      Xs[c4 * 4 + 0][xr] = vx.x;
      Xs[c4 * 4 + 1][xr] = vx.y;
      Xs[c4 * 4 + 2][xr] = vx.z;
      Xs[c4 * 4 + 3][xr] = vx.w;
    }
#pragma unroll
    for (int j = 0; j < 2; ++j) {
      const int c4 = wc + 16 * j;  // 0..31
      const float4 vw = *reinterpret_cast<const float4*>(
          &W[(size_t)(kt * 16 + wr) * NDM + n0 + c4 * 4]);
      *reinterpret_cast<float4*>(&Ws[wr][c4 * 4]) = vw;
    }
    __syncthreads();
#pragma unroll
    for (int kk = 0; kk < 16; ++kk) {
      float a[8], bb[8];
      *reinterpret_cast<float4*>(&a[0]) =
          *reinterpret_cast<const float4*>(&Xs[kk][ty * 8]);
      *reinterpret_cast<float4*>(&a[4]) =
          *reinterpret_cast<const float4*>(&Xs[kk][ty * 8 + 4]);
      *reinterpret_cast<float4*>(&bb[0]) =
          *reinterpret_cast<const float4*>(&Ws[kk][tx * 8]);
      *reinterpret_cast<float4*>(&bb[4]) =
          *reinterpret_cast<const float4*>(&Ws[kk][tx * 8 + 4]);
#pragma unroll
      for (int i = 0; i < 8; ++i)
#pragma unroll
        for (int j = 0; j < 8; ++j)
          acc[i][j] = fmaf(a[i], bb[j], acc[i][j]);
    }
    __syncthreads();
  }

#pragma unroll
  for (int i = 0; i < 8; ++i) {
    const int m  = m0 + ty * 8 + i;
    const int bb_ = m >> 11;        // / 2048
    const int ss  = m & (NS - 1);
#pragma unroll
    for (int j4 = 0; j4 < 2; ++j4) {
      const int n  = n0 + tx * 8 + j4 * 4;
      const int hh = n >> 6;
      const int dd = n & (ND - 1);
      const float4 bv4 = *reinterpret_cast<const float4*>(&bias[n]);
      float4 o;
      o.x = acc[i][j4 * 4 + 0] + bv4.x;
      o.y = acc[i][j4 * 4 + 1] + bv4.y;
      o.z = acc[i][j4 * 4 + 2] + bv4.z;
      o.w = acc[i][j4 * 4 + 3] + bv4.w;
      *reinterpret_cast<float4*>(
          &dst[(((size_t)bb_ * NH + hh) * NS + ss) * ND + dd]) = o;
    }
  }
}

// ---------------------------------------------------------------- attention
// Flash-style, fp32 compute. 1 wg per (bh, 64-row query block). 256 threads.
// LDS: Q/K fp16 (8K+8K), V fp32 (17K), E fp32 (32K), P fp16 [l][r] (8.5K)
//   = 73.5 KB -> 2 wg/CU (was 98 KB -> 1 wg/CU).
// scores[l][r] = q_l.k_r + (q_l + k_r).E_{l-r+2047}; /8; +mask; softmax; @V.
__launch_bounds__(256)
__global__ void attn_kernel(const float* __restrict__ q,   // [B,H,S,D]
                            const float* __restrict__ k,   // [B,H,S,D]
                            const float* __restrict__ v,   // [B,H,S,D]
                            const float* __restrict__ E,   // [4095, 64]
                            const float* __restrict__ mask,// [B*S]
                            float* __restrict__ out) {     // [B,S,DM]
  __shared__ __half Qs[ND][64];      // [i][l]    8 KB (transposed)
  __shared__ __half Ks[ND][64];      // [i][r]    8 KB (transposed)
  __shared__ float  Vs[64][ND + 4];  // [r][i]   17 KB (stride 17x16B: cf-free)
  __shared__ float  Es[ND][128];     // [i][dloc] 32 KB (transposed, dloc 0..126)
  __shared__ __half Ps[64][68];      // [l][r]    8.5 KB

  const int t  = threadIdx.x;
  const int tx = t & 15;   // r-group / d-group (4 each)
  const int ty = t >> 4;   // l-group (4 each)
  const int l0 = blockIdx.x * 64;
  const int bh = blockIdx.y;
  const int b  = bh / NH;
  const int h  = bh % NH;

  const float* qp = q + ((size_t)bh * NS + l0) * ND;
  const float* kp = k + (size_t)bh * NS * ND;
  const float* vp = v + (size_t)bh * NS * ND;

  // stage Q transposed, fp16 (once)
  {
    const int rr = t & 63;
    const int w  = t >> 6;
#pragma unroll
    for (int j = 0; j < 4; ++j) {
      const int c = w * 4 + j;
      const float4 val =
          *reinterpret_cast<const float4*>(&qp[(size_t)rr * ND + c * 4]);
      Qs[c * 4 + 0][rr] = __float2half(val.x);
      Qs[c * 4 + 1][rr] = __float2half(val.y);
      Qs[c * 4 + 2][rr] = __float2half(val.z);
      Qs[c * 4 + 3][rr] = __float2half(val.w);
    }
  }

  float O[4][4];
  float m_run[4], l_run[4];
#pragma unroll
  for (int i = 0; i < 4; ++i) {
    m_run[i] = -1e30f;
    l_run[i] = 0.f;
#pragma unroll
    for (int j = 0; j < 4; ++j) O[i][j] = 0.f;
  }

  for (int r0 = 0; r0 < NS; r0 += 64) {
    __syncthreads();  // prev-iter PV done before restage
    // stage K fp16 (transposed) and V fp32 (row-major)
    {
      const int rr = t & 63;
      const int w  = t >> 6;
#pragma unroll
      for (int j = 0; j < 4; ++j) {
        const int c = w * 4 + j;
        const float4 kv4 = *reinterpret_cast<const float4*>(
            &kp[(size_t)(r0 + rr) * ND + c * 4]);
        Ks[c * 4 + 0][rr] = __float2half(kv4.x);
        Ks[c * 4 + 1][rr] = __float2half(kv4.y);
        Ks[c * 4 + 2][rr] = __float2half(kv4.z);
        Ks[c * 4 + 3][rr] = __float2half(kv4.w);
        const float4 vv4 = *reinterpret_cast<const float4*>(
            &vp[(size_t)(r0 + rr) * ND + c * 4]);
        *reinterpret_cast<float4*>(&Vs[rr][c * 4]) = vv4;
      }
    }
    // stage E slice (transposed): d_global = (l0-r0+2047) - 63 + dloc, dloc 0..126
    {
      const int dloc = t >> 1;
      const int half = t & 1;
      if (dloc < 127) {
        const float* ep =
            E + (size_t)(l0 - r0 + (NS - 1) - 63 + dloc) * ND + half * 32;
#pragma unroll
        for (int j = 0; j < 8; ++j) {
          const float4 val = *reinterpret_cast<const float4*>(&ep[j * 4]);
          const int i = half * 32 + j * 4;
          Es[i + 0][dloc] = val.x;
          Es[i + 1][dloc] = val.y;
          Es[i + 2][dloc] = val.z;
          Es[i + 3][dloc] = val.w;
        }
      }
    }
    __syncthreads();

    // ---- scores: 4l x 4r per thread
    float sc[4][4];
#pragma unroll
    for (int a = 0; a < 4; ++a)
#pragma unroll
      for (int c = 0; c < 4; ++c) sc[a][c] = 0.f;

    const int eb = (ty - tx) * 4 + 60;  // aligned base; needed dloc = eb+3+jl-jr
#pragma unroll 4
    for (int i = 0; i < ND; ++i) {
      float qv[4], kv[4], ev[8];
      {
        const __half2 qa = *reinterpret_cast<const __half2*>(&Qs[i][ty * 4]);
        const __half2 qb =
            *reinterpret_cast<const __half2*>(&Qs[i][ty * 4 + 2]);
        const float2 f0 = __half22float2(qa);
        const float2 f1 = __half22float2(qb);
        qv[0] = f0.x; qv[1] = f0.y; qv[2] = f1.x; qv[3] = f1.y;
        const __half2 ka = *reinterpret_cast<const __half2*>(&Ks[i][tx * 4]);
        const __half2 kb =
            *reinterpret_cast<const __half2*>(&Ks[i][tx * 4 + 2]);
        const float2 g0 = __half22float2(ka);
        const float2 g1 = __half22float2(kb);
        kv[0] = g0.x; kv[1] = g0.y; kv[2] = g1.x; kv[3] = g1.y;
      }
      *reinterpret_cast<float4*>(&ev[0]) =
          *reinterpret_cast<const float4*>(&Es[i][eb]);
      *reinterpret_cast<float4*>(&ev[4]) =
          *reinterpret_cast<const float4*>(&Es[i][eb + 4]);
#pragma unroll
      for (int jl = 0; jl < 4; ++jl)
#pragma unroll
        for (int jr = 0; jr < 4; ++jr) {
          sc[jl][jr] = fmaf(qv[jl], kv[jr], sc[jl][jr]);
          sc[jl][jr] = fmaf(qv[jl] + kv[jr], ev[3 + jl - jr], sc[jl][jr]);
        }
    }

    // ---- online softmax
    float mk[4];
    {
      const float4 m4 = *reinterpret_cast<const float4*>(
          &mask[(size_t)b * NS + r0 + tx * 4]);
      mk[0] = m4.x; mk[1] = m4.y; mk[2] = m4.z; mk[3] = m4.w;
    }
    float mrow[4];
#pragma unroll
    for (int jl = 0; jl < 4; ++jl) {
      float mx = -1e30f;
#pragma unroll
      for (int jr = 0; jr < 4; ++jr) {
        const float val = sc[jl][jr] * 0.125f + mk[jr];
        sc[jl][jr] = val;
        mx = fmaxf(mx, val);
      }
      mrow[jl] = mx;
    }
#pragma unroll
    for (int off = 1; off < 16; off <<= 1)
#pragma unroll
      for (int jl = 0; jl < 4; ++jl)
        mrow[jl] = fmaxf(mrow[jl], __shfl_xor(mrow[jl], off));

    float pr[4][4], alpha[4], psum[4];
#pragma unroll
    for (int jl = 0; jl < 4; ++jl) {
      const float mnew = fmaxf(m_run[jl], mrow[jl]);
      alpha[jl] = __expf(m_run[jl] - mnew);
      m_run[jl] = mnew;
      float ps = 0.f;
#pragma unroll
      for (int jr = 0; jr < 4; ++jr) {
        const float p = __expf(sc[jl][jr] - mnew);
        pr[jl][jr] = p;
        ps += p;
      }
      psum[jl] = ps;
    }
#pragma unroll
    for (int off = 1; off < 16; off <<= 1)
#pragma unroll
      for (int jl = 0; jl < 4; ++jl) psum[jl] += __shfl_xor(psum[jl], off);
#pragma unroll
    for (int jl = 0; jl < 4; ++jl) {
      l_run[jl] = l_run[jl] * alpha[jl] + psum[jl];
#pragma unroll
      for (int jd = 0; jd < 4; ++jd) O[jl][jd] *= alpha[jl];
    }
    // write P fp16, [l][r] layout: per jl a contiguous 4-half (8B) store
#pragma unroll
    for (int jl = 0; jl < 4; ++jl) {
      __half2* pp =
          reinterpret_cast<__half2*>(&Ps[ty * 4 + jl][tx * 4]);
      pp[0] = __floats2half2_rn(pr[jl][0], pr[jl][1]);
      pp[1] = __floats2half2_rn(pr[jl][2], pr[jl][3]);
    }
    __syncthreads();

    // ---- PV: O[l][d] += sum_r P[l][r] * V[r][d]
#pragma unroll 4
    for (int rq = 0; rq < 16; ++rq) {
      float pl[4][4];
#pragma unroll
      for (int jl = 0; jl < 4; ++jl) {
        const __half2 a =
            *reinterpret_cast<const __half2*>(&Ps[ty * 4 + jl][rq * 4]);
        const __half2 bq =
            *reinterpret_cast<const __half2*>(&Ps[ty * 4 + jl][rq * 4 + 2]);
        const float2 f0 = __half22float2(a);
        const float2 f1 = __half22float2(bq);
        pl[jl][0] = f0.x; pl[jl][1] = f0.y; pl[jl][2] = f1.x; pl[jl][3] = f1.y;
      }
#pragma unroll
      for (int u = 0; u < 4; ++u) {
        const float4 v4 =
            *reinterpret_cast<const float4*>(&Vs[rq * 4 + u][tx * 4]);
        const float va[4] = {v4.x, v4.y, v4.z, v4.w};
#pragma unroll
        for (int jl = 0; jl < 4; ++jl)
#pragma unroll
          for (int jd = 0; jd < 4; ++jd)
            O[jl][jd] = fmaf(pl[jl][u], va[jd], O[jl][jd]);
      }
    }
  }

  // epilogue: normalize and store [B,S,DM]
#pragma unroll
  for (int jl = 0; jl < 4; ++jl) {
    const float inv = 1.0f / l_run[jl];
    const int l = l0 + ty * 4 + jl;
    float4 o;
    o.x = O[jl][0] * inv;
    o.y = O[jl][1] * inv;
    o.z = O[jl][2] * inv;
    o.w = O[jl][3] * inv;
    *reinterpret_cast<float4*>(
        &out[((size_t)b * NS + l) * NDM + h * ND + tx * 4]) = o;
  }
}

extern "C" void kernel_launch(void* const* d_in, const int* in_sizes, int n_in,
                              void* d_out, int out_size, void* d_ws, size_t ws_size,
                              hipStream_t stream) {
  const float* hs  = (const float*)d_in[0];
  const float* msk = (const float*)d_in[1];
  const float* Wq  = (const float*)d_in[2];
  const float* bq  = (const float*)d_in[3];
  const float* Wk  = (const float*)d_in[4];
  const float* bk  = (const float*)d_in[5];
  const float* Wv  = (const float*)d_in[6];
  const float* bv  = (const float*)d_in[7];
  const float* Ept = (const float*)d_in[8];
  float* out = (float*)d_out;

  const size_t per = (size_t)NB * NH * NS * ND;  // 3,145,728 floats
  float* qb = (float*)d_ws;
  float* kb = qb + per;
  float* vb = kb + per;

  dim3 gg(NDM / 128, (NB * NS) / 128);  // (6, 32)
  qkv_gemm<<<gg, 256, 0, stream>>>(hs, Wq, bq, qb);
  qkv_gemm<<<gg, 256, 0, stream>>>(hs, Wk, bk, kb);
  qkv_gemm<<<gg, 256, 0, stream>>>(hs, Wv, bv, vb);

  attn_kernel<<<dim3(NS / 64, NB * NH), 256, 0, stream>>>(qb, kb, vb, Ept,
                                                          msk, out);
}

// Round 3
// 777.365 us; speedup vs baseline: 1.8403x; 1.6065x over previous
//
#include <hip/hip_runtime.h>
#include <hip/hip_fp16.h>

#define NB 2
#define NS 2048
#define NDM 768
#define NH 12
#define ND 64
// dist_emb rows = 2*NS - 1 = 4095

typedef __attribute__((ext_vector_type(8))) _Float16 f16x8;
typedef __attribute__((ext_vector_type(4))) float f32x4;

// ---------------------------------------------------------------- QKV GEMM
// (unchanged from round 1 — fp32 VALU, ~97 us each; MFMA-ify next round)
__launch_bounds__(256)
__global__ void qkv_gemm(const float* __restrict__ X,
                         const float* __restrict__ W,
                         const float* __restrict__ bias,
                         float* __restrict__ dst) {
  __shared__ float Xs[16][128];
  __shared__ float Ws[16][132];

  const int t  = threadIdx.x;
  const int tx = t & 15;
  const int ty = t >> 4;
  const int m0 = blockIdx.y * 128;
  const int n0 = blockIdx.x * 128;

  float acc[8][8];
#pragma unroll
  for (int i = 0; i < 8; ++i)
#pragma unroll
    for (int j = 0; j < 8; ++j) acc[i][j] = 0.f;

  const int xr = t & 127;
  const int xc = t >> 7;
  const int wr = t & 15;
  const int wc = t >> 4;

  for (int kt = 0; kt < NDM / 16; ++kt) {
#pragma unroll
    for (int j = 0; j < 2; ++j) {
      const int c4 = xc * 2 + j;
      const float4 vx = *reinterpret_cast<const float4*>(
          &X[(size_t)(m0 + xr) * NDM + kt * 16 + c4 * 4]);
      Xs[c4 * 4 + 0][xr] = vx.x;
      Xs[c4 * 4 + 1][xr] = vx.y;
      Xs[c4 * 4 + 2][xr] = vx.z;
      Xs[c4 * 4 + 3][xr] = vx.w;
    }
#pragma unroll
    for (int j = 0; j < 2; ++j) {
      const int c4 = wc + 16 * j;
      const float4 vw = *reinterpret_cast<const float4*>(
          &W[(size_t)(kt * 16 + wr) * NDM + n0 + c4 * 4]);
      *reinterpret_cast<float4*>(&Ws[wr][c4 * 4]) = vw;
    }
    __syncthreads();
#pragma unroll
    for (int kk = 0; kk < 16; ++kk) {
      float a[8], bb[8];
      *reinterpret_cast<float4*>(&a[0]) =
          *reinterpret_cast<const float4*>(&Xs[kk][ty * 8]);
      *reinterpret_cast<float4*>(&a[4]) =
          *reinterpret_cast<const float4*>(&Xs[kk][ty * 8 + 4]);
      *reinterpret_cast<float4*>(&bb[0]) =
          *reinterpret_cast<const float4*>(&Ws[kk][tx * 8]);
      *reinterpret_cast<float4*>(&bb[4]) =
          *reinterpret_cast<const float4*>(&Ws[kk][tx * 8 + 4]);
#pragma unroll
      for (int i = 0; i < 8; ++i)
#pragma unroll
        for (int j = 0; j < 8; ++j)
          acc[i][j] = fmaf(a[i], bb[j], acc[i][j]);
    }
    __syncthreads();
  }

#pragma unroll
  for (int i = 0; i < 8; ++i) {
    const int m   = m0 + ty * 8 + i;
    const int bb_ = m >> 11;
    const int ss  = m & (NS - 1);
#pragma unroll
    for (int j4 = 0; j4 < 2; ++j4) {
      const int n  = n0 + tx * 8 + j4 * 4;
      const int hh = n >> 6;
      const int dd = n & (ND - 1);
      const float4 bv4 = *reinterpret_cast<const float4*>(&bias[n]);
      float4 o;
      o.x = acc[i][j4 * 4 + 0] + bv4.x;
      o.y = acc[i][j4 * 4 + 1] + bv4.y;
      o.z = acc[i][j4 * 4 + 2] + bv4.z;
      o.w = acc[i][j4 * 4 + 3] + bv4.w;
      *reinterpret_cast<float4*>(
          &dst[(((size_t)bb_ * NH + hh) * NS + ss) * ND + dd]) = o;
    }
  }
}

// ---------------------------------------------------------------- attention
// MFMA flash attention. 4 waves (256 thr), QBLK=64, KVBLK=32, 64 kv-iters.
// Per iter: S0 = Q.K^T (MFMA), F1 = Q.Ew^T, F2 = K.Ew^T (MFMA, Ew = 95-row
// dist_emb window), scores = (S0 + F1[ll][dloc] + F2[rl][dloc])/8 + mask with
// dloc = ll-rl+31 (diagonal gather), online softmax, O += P.V (MFMA).
// f16 operand tiles XOR-swizzled (16B blocks, row&7); F1/F2/P f32 in LDS.
// LDS = 75.5 KB -> 2 wg/CU.
// Fragment maps (m89): C row=4g+j col=L; A row=L k=8g+i; B col=L k=8g+i.
__launch_bounds__(256, 2)
__global__ void attn_mfma(const float* __restrict__ q,   // [B,H,S,D]
                          const float* __restrict__ k,   // [B,H,S,D]
                          const float* __restrict__ v,   // [B,H,S,D]
                          const float* __restrict__ E,   // [4095, 64]
                          const float* __restrict__ mask,// [B*S]
                          float* __restrict__ out) {     // [B,S,DM]
  __shared__ __align__(16) __half Qs[64 * 64];   //  8 KB, swizzled [l][d]
  __shared__ __align__(16) __half Ks[32 * 64];   //  4 KB, swizzled [r][d]
  __shared__ __align__(16) __half Es[96 * 64];   // 12 KB, swizzled [dloc][d]
  __shared__ __align__(16) __half Vt[64 * 40];   //  5 KB, [d][r] pad 40
  __shared__ float F1s[64 * 100];                // 25.6 KB [ll][dloc]
  __shared__ float F2s[32 * 100];                // 12.8 KB [rl][dloc]
  __shared__ float Ps[64 * 36];                  //  9.2 KB [ll][rl]

  const int t    = threadIdx.x;
  const int lane = t & 63;
  const int w    = t >> 6;     // wave 0..3, owns l-rows [16w,16w+16)
  const int g    = lane >> 4;  // lane group 0..3
  const int L    = lane & 15;
  const int l0   = blockIdx.x * 64;
  const int bh   = blockIdx.y;
  const int b    = bh / NH;
  const int h    = bh - b * NH;

  const float* qp = q + ((size_t)bh * NS + l0) * ND;
  const float* kp = k + (size_t)bh * NS * ND;
  const float* vp = v + (size_t)bh * NS * ND;
  const float* mp = mask + (size_t)b * NS;

  // ---- stage Q once: f16, row-swizzled (16B block ^= row&7)
#pragma unroll
  for (int s = 0; s < 4; ++s) {
    const int tau = t + 256 * s;
    const int r = tau >> 4, qd = tau & 15;
    const float4 x =
        *reinterpret_cast<const float4*>(&qp[(size_t)r * ND + qd * 4]);
    union { __half2 h2[2]; uint2 u; } pk;
    pk.h2[0] = __floats2half2_rn(x.x, x.y);
    pk.h2[1] = __floats2half2_rn(x.z, x.w);
    const int idx = r * 64 + ((((qd >> 1) ^ (r & 7)) << 3) | ((qd & 1) << 2));
    *reinterpret_cast<uint2*>(&Qs[idx]) = pk.u;
  }

  f32x4 Oacc[4];
  float m_run[4], l_run[4];
#pragma unroll
  for (int j = 0; j < 4; ++j) { m_run[j] = -1e30f; l_run[j] = 0.f; }
#pragma unroll
  for (int nt = 0; nt < 4; ++nt) Oacc[nt] = {0.f, 0.f, 0.f, 0.f};

  const int rtw    = w >> 1;        // F2 row-tile owned by this wave
  const int dtbase = (w & 1) * 3;   // F2 d-tiles owned: dtbase..dtbase+2
  const int swL    = L & 7;
  const f32x4 Z = {0.f, 0.f, 0.f, 0.f};

  for (int r0 = 0; r0 < NS; r0 += 32) {
    __syncthreads();  // prev PV reads done before restage

    // ---- stage K (f16 swizzled)
#pragma unroll
    for (int s = 0; s < 2; ++s) {
      const int tau = t + 256 * s;
      const int r = tau >> 4, qd = tau & 15;
      const float4 x = *reinterpret_cast<const float4*>(
          &kp[(size_t)(r0 + r) * ND + qd * 4]);
      union { __half2 h2[2]; uint2 u; } pk;
      pk.h2[0] = __floats2half2_rn(x.x, x.y);
      pk.h2[1] = __floats2half2_rn(x.z, x.w);
      const int idx =
          r * 64 + ((((qd >> 1) ^ (r & 7)) << 3) | ((qd & 1) << 2));
      *reinterpret_cast<uint2*>(&Ks[idx]) = pk.u;
    }
    // ---- stage V transposed [d][r] (global scatter-read, clean LDS write)
#pragma unroll
    for (int s = 0; s < 2; ++s) {
      const int tau = t + 256 * s;
      const int rr = tau & 31, qd = tau >> 5;
      const float4 x = *reinterpret_cast<const float4*>(
          &vp[(size_t)(r0 + rr) * ND + qd * 4]);
      Vt[(qd * 4 + 0) * 40 + rr] = __float2half(x.x);
      Vt[(qd * 4 + 1) * 40 + rr] = __float2half(x.y);
      Vt[(qd * 4 + 2) * 40 + rr] = __float2half(x.z);
      Vt[(qd * 4 + 3) * 40 + rr] = __float2half(x.w);
    }
    // ---- stage E window: rows 0..95, global row = start + row (clamped)
    const int start = l0 - r0 + 2016;  // = l0-r0+2047-31
#pragma unroll
    for (int s = 0; s < 3; ++s) {
      const int tau = t + 256 * s;
      const int row = tau >> 3, blk = tau & 7;
      int grow = start + row;
      grow = grow > 4094 ? 4094 : grow;  // row 95 pad, never gathered
      const float* ep = &E[(size_t)grow * ND + blk * 8];
      const float4 a = *reinterpret_cast<const float4*>(ep);
      const float4 c = *reinterpret_cast<const float4*>(ep + 4);
      union { __half2 h2[4]; uint4 u; } pk;
      pk.h2[0] = __floats2half2_rn(a.x, a.y);
      pk.h2[1] = __floats2half2_rn(a.z, a.w);
      pk.h2[2] = __floats2half2_rn(c.x, c.y);
      pk.h2[3] = __floats2half2_rn(c.z, c.w);
      *reinterpret_cast<uint4*>(&Es[row * 64 + ((blk ^ (row & 7)) << 3)]) =
          pk.u;
    }
    __syncthreads();

    // ---- operand fragments (all b128, conflict-free via swizzle)
    const int rq = 16 * w + L;
    const f16x8 aQ0 = *reinterpret_cast<const f16x8*>(
        &Qs[rq * 64 + ((g ^ swL) << 3)]);
    const f16x8 aQ1 = *reinterpret_cast<const f16x8*>(
        &Qs[rq * 64 + (((4 + g) ^ swL) << 3)]);
    const f16x8 bK00 = *reinterpret_cast<const f16x8*>(
        &Ks[L * 64 + ((g ^ swL) << 3)]);
    const f16x8 bK01 = *reinterpret_cast<const f16x8*>(
        &Ks[L * 64 + (((4 + g) ^ swL) << 3)]);
    const f16x8 bK10 = *reinterpret_cast<const f16x8*>(
        &Ks[(16 + L) * 64 + ((g ^ swL) << 3)]);
    const f16x8 bK11 = *reinterpret_cast<const f16x8*>(
        &Ks[(16 + L) * 64 + (((4 + g) ^ swL) << 3)]);

    // S0 = Q.K^T  (K=64 -> 2 mfma per r-tile)
    f32x4 c0 = Z, c1 = Z;
    c0 = __builtin_amdgcn_mfma_f32_16x16x32_f16(aQ0, bK00, c0, 0, 0, 0);
    c0 = __builtin_amdgcn_mfma_f32_16x16x32_f16(aQ1, bK01, c0, 0, 0, 0);
    c1 = __builtin_amdgcn_mfma_f32_16x16x32_f16(aQ0, bK10, c1, 0, 0, 0);
    c1 = __builtin_amdgcn_mfma_f32_16x16x32_f16(aQ1, bK11, c1, 0, 0, 0);

    // F1 = Q.Ew^T  (own l-tile x 6 d-tiles)
    f32x4 f1acc[6];
#pragma unroll
    for (int dt = 0; dt < 6; ++dt) {
      const int re = 16 * dt + L;
      const f16x8 be0 = *reinterpret_cast<const f16x8*>(
          &Es[re * 64 + ((g ^ swL) << 3)]);
      const f16x8 be1 = *reinterpret_cast<const f16x8*>(
          &Es[re * 64 + (((4 + g) ^ swL) << 3)]);
      f32x4 acc = Z;
      acc = __builtin_amdgcn_mfma_f32_16x16x32_f16(aQ0, be0, acc, 0, 0, 0);
      acc = __builtin_amdgcn_mfma_f32_16x16x32_f16(aQ1, be1, acc, 0, 0, 0);
      f1acc[dt] = acc;
    }
    // F2 = K.Ew^T  (wave's (rtw, dtbase..+2) share; A-frag == bK regs)
    const f16x8 aK0 = rtw ? bK10 : bK00;
    const f16x8 aK1 = rtw ? bK11 : bK01;
    f32x4 f2acc[3];
#pragma unroll
    for (int m = 0; m < 3; ++m) {
      const int re = 16 * (dtbase + m) + L;
      const f16x8 be0 = *reinterpret_cast<const f16x8*>(
          &Es[re * 64 + ((g ^ swL) << 3)]);
      const f16x8 be1 = *reinterpret_cast<const f16x8*>(
          &Es[re * 64 + (((4 + g) ^ swL) << 3)]);
      f32x4 acc = Z;
      acc = __builtin_amdgcn_mfma_f32_16x16x32_f16(aK0, be0, acc, 0, 0, 0);
      acc = __builtin_amdgcn_mfma_f32_16x16x32_f16(aK1, be1, acc, 0, 0, 0);
      f2acc[m] = acc;
    }

    // ---- write F1, F2 (b32, 2-way max via pad 100)
#pragma unroll
    for (int dt = 0; dt < 6; ++dt)
#pragma unroll
      for (int j = 0; j < 4; ++j)
        F1s[(16 * w + 4 * g + j) * 100 + 16 * dt + L] = f1acc[dt][j];
#pragma unroll
    for (int m = 0; m < 3; ++m)
#pragma unroll
      for (int j = 0; j < 4; ++j)
        F2s[(16 * rtw + 4 * g + j) * 100 + 16 * (dtbase + m) + L] =
            f2acc[m][j];
    __syncthreads();

    // ---- assemble scores + diagonal gather + online softmax
    float sc2[2][4];
    const float mk0 = mp[r0 + L];
    const float mk1 = mp[r0 + 16 + L];
#pragma unroll
    for (int j = 0; j < 4; ++j) {
      const int ll = 16 * w + 4 * g + j;
      {
        const int dl = ll - L + 31;
        sc2[0][j] =
            (c0[j] + F1s[ll * 100 + dl] + F2s[L * 100 + dl]) * 0.125f + mk0;
      }
      {
        const int rl = 16 + L;
        const int dl = ll - rl + 31;
        sc2[1][j] =
            (c1[j] + F1s[ll * 100 + dl] + F2s[rl * 100 + dl]) * 0.125f + mk1;
      }
    }
    float al[4];
#pragma unroll
    for (int j = 0; j < 4; ++j) {
      float mx = fmaxf(sc2[0][j], sc2[1][j]);
      mx = fmaxf(mx, __shfl_xor(mx, 1));
      mx = fmaxf(mx, __shfl_xor(mx, 2));
      mx = fmaxf(mx, __shfl_xor(mx, 4));
      mx = fmaxf(mx, __shfl_xor(mx, 8));
      const float mnew = fmaxf(m_run[j], mx);
      al[j] = __expf(m_run[j] - mnew);
      m_run[j] = mnew;
      const float p0 = __expf(sc2[0][j] - mnew);
      const float p1 = __expf(sc2[1][j] - mnew);
      sc2[0][j] = p0;
      sc2[1][j] = p1;
      float ps = p0 + p1;
      ps += __shfl_xor(ps, 1);
      ps += __shfl_xor(ps, 2);
      ps += __shfl_xor(ps, 4);
      ps += __shfl_xor(ps, 8);
      l_run[j] = l_run[j] * al[j] + ps;
    }
#pragma unroll
    for (int nt = 0; nt < 4; ++nt)
#pragma unroll
      for (int j = 0; j < 4; ++j) Oacc[nt][j] *= al[j];
#pragma unroll
    for (int j = 0; j < 4; ++j) {
      Ps[(16 * w + 4 * g + j) * 36 + L]      = sc2[0][j];
      Ps[(16 * w + 4 * g + j) * 36 + 16 + L] = sc2[1][j];
    }
    __syncthreads();

    // ---- PV: O += P.V  (K=32 -> 1 mfma per d-tile)
    {
      const float* pr = &Ps[(size_t)(16 * w + L) * 36 + 8 * g];
      const float4 pa = *reinterpret_cast<const float4*>(pr);
      const float4 pb = *reinterpret_cast<const float4*>(pr + 4);
      f16x8 aP;
      aP[0] = (_Float16)pa.x; aP[1] = (_Float16)pa.y;
      aP[2] = (_Float16)pa.z; aP[3] = (_Float16)pa.w;
      aP[4] = (_Float16)pb.x; aP[5] = (_Float16)pb.y;
      aP[6] = (_Float16)pb.z; aP[7] = (_Float16)pb.w;
#pragma unroll
      for (int nt = 0; nt < 4; ++nt) {
        const f16x8 bV = *reinterpret_cast<const f16x8*>(
            &Vt[(16 * nt + L) * 40 + 8 * g]);
        Oacc[nt] = __builtin_amdgcn_mfma_f32_16x16x32_f16(aP, bV, Oacc[nt],
                                                          0, 0, 0);
      }
    }
  }

  // ---- epilogue: normalize, store [B,S,DM]
#pragma unroll
  for (int j = 0; j < 4; ++j) {
    const float inv = 1.0f / l_run[j];
    const int row = l0 + 16 * w + 4 * g + j;
    float* op = &out[((size_t)b * NS + row) * NDM + h * ND + L];
    op[0]  = Oacc[0][j] * inv;
    op[16] = Oacc[1][j] * inv;
    op[32] = Oacc[2][j] * inv;
    op[48] = Oacc[3][j] * inv;
  }
}

extern "C" void kernel_launch(void* const* d_in, const int* in_sizes, int n_in,
                              void* d_out, int out_size, void* d_ws, size_t ws_size,
                              hipStream_t stream) {
  const float* hs  = (const float*)d_in[0];
  const float* msk = (const float*)d_in[1];
  const float* Wq  = (const float*)d_in[2];
  const float* bq  = (const float*)d_in[3];
  const float* Wk  = (const float*)d_in[4];
  const float* bk  = (const float*)d_in[5];
  const float* Wv  = (const float*)d_in[6];
  const float* bv  = (const float*)d_in[7];
  const float* Ept = (const float*)d_in[8];
  float* out = (float*)d_out;

  const size_t per = (size_t)NB * NH * NS * ND;  // 3,145,728 floats
  float* qb = (float*)d_ws;
  float* kb = qb + per;
  float* vb = kb + per;

  dim3 gg(NDM / 128, (NB * NS) / 128);  // (6, 32)
  qkv_gemm<<<gg, 256, 0, stream>>>(hs, Wq, bq, qb);
  qkv_gemm<<<gg, 256, 0, stream>>>(hs, Wk, bk, kb);
  qkv_gemm<<<gg, 256, 0, stream>>>(hs, Wv, bv, vb);

  attn_mfma<<<dim3(NS / 64, NB * NH), 256, 0, stream>>>(qb, kb, vb, Ept,
                                                        msk, out);
}

// Round 5
// 637.015 us; speedup vs baseline: 2.2457x; 1.2203x over previous
//
#include <hip/hip_runtime.h>
#include <hip/hip_fp16.h>

#define NB 2
#define NS 2048
#define NDM 768
#define NH 12
#define ND 64
// dist_emb rows = 2*NS - 1 = 4095

typedef __attribute__((ext_vector_type(8))) _Float16 f16x8;
typedef __attribute__((ext_vector_type(4))) float f32x4;

// swizzle for [row][32-half] GEMM tiles: 16B-block idx XOR (full 16-row spread)
__device__ __forceinline__ int swz(int row) {
  return (row & 3) ^ ((row >> 2) & 3);
}

// ------------------------------------------------------- split-f16 converts
// X [4096x768] f32 -> Xh, Xl f16 (same layout). Exact grid: 3072 x 256.
__launch_bounds__(256)
__global__ void cvt_split(const float* __restrict__ x, __half* __restrict__ xh,
                          __half* __restrict__ xl) {
  const int i = blockIdx.x * 256 + threadIdx.x;  // one float4
  const float4 v = reinterpret_cast<const float4*>(x)[i];
  const float a[4] = {v.x, v.y, v.z, v.w};
  union { __half h[4]; uint2 u; } ph, pl;
#pragma unroll
  for (int j = 0; j < 4; ++j) {
    ph.h[j] = __float2half(a[j]);
    pl.h[j] = __float2half(a[j] - __half2float(ph.h[j]));
  }
  *reinterpret_cast<uint2*>(&xh[(size_t)i * 4]) = ph.u;
  *reinterpret_cast<uint2*>(&xl[(size_t)i * 4]) = pl.u;
}

// W [768k x 768n] f32 -> WhT, WlT [n][k] f16 (transposed), 3 matrices.
// grid (12 k-tiles, 12 n-tiles, 3).
__launch_bounds__(256)
__global__ void cvt_w_t(const float* __restrict__ Wq,
                        const float* __restrict__ Wk,
                        const float* __restrict__ Wv,
                        __half* __restrict__ WhT, __half* __restrict__ WlT) {
  __shared__ float Tf[64][65];
  const int t = threadIdx.x;
  const int k0 = blockIdx.x * 64;
  const int n0 = blockIdx.y * 64;
  const int z = blockIdx.z;
  const float* W = z == 0 ? Wq : (z == 1 ? Wk : Wv);
  __half* wh = WhT + (size_t)z * NDM * NDM;
  __half* wl = WlT + (size_t)z * NDM * NDM;
#pragma unroll
  for (int s = 0; s < 4; ++s) {
    const int lin = t + 256 * s;
    const int r = lin >> 4, c4 = (lin & 15) * 4;
    const float4 v = *reinterpret_cast<const float4*>(
        &W[(size_t)(k0 + r) * NDM + n0 + c4]);
    Tf[r][c4 + 0] = v.x;
    Tf[r][c4 + 1] = v.y;
    Tf[r][c4 + 2] = v.z;
    Tf[r][c4 + 3] = v.w;
  }
  __syncthreads();
#pragma unroll
  for (int s = 0; s < 4; ++s) {
    const int lin = t + 256 * s;
    const int nl = lin >> 4, k4 = (lin & 15) * 4;
    union { __half h[4]; uint2 u; } ph, pl;
#pragma unroll
    for (int i = 0; i < 4; ++i) {
      const float f = Tf[k4 + i][nl];
      ph.h[i] = __float2half(f);
      pl.h[i] = __float2half(f - __half2float(ph.h[i]));
    }
    *reinterpret_cast<uint2*>(&wh[(size_t)(n0 + nl) * NDM + k0 + k4]) = ph.u;
    *reinterpret_cast<uint2*>(&wl[(size_t)(n0 + nl) * NDM + k0 + k4]) = pl.u;
  }
}

// ---------------------------------------------------------------- QKV GEMM
// Fused split-f16 MFMA GEMM: M=4096, N=3x768, K=768. acc = Xh.Wh + Xh.Wl +
// Xl.Wh (fp32-exact to ~2e-7 rel). 128x128x32 tiles, 4 waves (2x2), each
// 64x64 out = 4x4 C-frags. Reg-staged single LDS buffer, prefetch-early.
// LDS tiles [row][32] halfs, 16B-block XOR swizzle -> 2-way (free) ds_read.
// Output written f16 directly in [B,H,S,D].
// NOTE: single SS[4][...] LDS array (runtime-indexed by buffer selector);
// an array of pointers to distinct __shared__ arrays fails gfx950 codegen
// ("unsupported expression in static initializer: addrspacecast").
__launch_bounds__(256, 2)
__global__ void qkv_mfma(const __half* __restrict__ Xh,
                         const __half* __restrict__ Xl,
                         const __half* __restrict__ WhT,  // [3][768n][768k]
                         const __half* __restrict__ WlT,
                         const float* __restrict__ bq,
                         const float* __restrict__ bk,
                         const float* __restrict__ bv,
                         __half* __restrict__ qb, __half* __restrict__ kb,
                         __half* __restrict__ vb) {
  __shared__ __align__(16) __half SS[4][128 * 32];  // Ah, Al, Bh, Bl

  const int t = threadIdx.x;
  const int lane = t & 63;
  const int w = t >> 6;
  const int g = lane >> 4;
  const int L = lane & 15;
  const int wm = w & 1, wn = w >> 1;
  const int widx = blockIdx.x / 6;          // 0=q 1=k 2=v
  const int n0m = (blockIdx.x % 6) * 128;   // n within the matrix
  const int m0 = blockIdx.y * 128;

  const __half* wh = WhT + (size_t)widx * NDM * NDM;
  const __half* wl = WlT + (size_t)widx * NDM * NDM;
  const float* bias = widx == 0 ? bq : (widx == 1 ? bk : bv);
  __half* dst = widx == 0 ? qb : (widx == 1 ? kb : vb);

  const __half* srcs[4] = {Xh + (size_t)m0 * NDM, Xl + (size_t)m0 * NDM,
                           wh + (size_t)n0m * NDM, wl + (size_t)n0m * NDM};

  // prefetch K-step 0 into regs
  uint4 rv[8];
#pragma unroll
  for (int u = 0; u < 8; ++u) {
    const int slot = t + 256 * u;
    const int bsel = slot >> 9, within = slot & 511;
    const int row = within >> 2, blk = within & 3;
    rv[u] = *reinterpret_cast<const uint4*>(srcs[bsel] + (size_t)row * NDM +
                                            blk * 8);
  }

  f32x4 acc[4][4];
#pragma unroll
  for (int mt = 0; mt < 4; ++mt)
#pragma unroll
    for (int nt = 0; nt < 4; ++nt) acc[mt][nt] = {0.f, 0.f, 0.f, 0.f};

  const int sL = (L & 3) ^ ((L >> 2) & 3);
  const int gs = (g ^ sL) << 3;  // frag sub-offset (halfs)

  for (int kt = 0; kt < 24; ++kt) {
    __syncthreads();  // prior compute done reading LDS
#pragma unroll
    for (int u = 0; u < 8; ++u) {
      const int slot = t + 256 * u;
      const int bsel = slot >> 9, within = slot & 511;
      const int row = within >> 2, blk = within & 3;
      *reinterpret_cast<uint4*>(&SS[bsel][row * 32 + ((blk ^ swz(row)) << 3)]) =
          rv[u];
    }
    if (kt < 23) {
      const int k0 = (kt + 1) * 32;
#pragma unroll
      for (int u = 0; u < 8; ++u) {
        const int slot = t + 256 * u;
        const int bsel = slot >> 9, within = slot & 511;
        const int row = within >> 2, blk = within & 3;
        rv[u] = *reinterpret_cast<const uint4*>(
            srcs[bsel] + (size_t)row * NDM + k0 + blk * 8);
      }
    }
    __syncthreads();  // LDS writes visible

    f16x8 bh[4], bl[4];
#pragma unroll
    for (int nt = 0; nt < 4; ++nt) {
      const int nl = 64 * wn + 16 * nt + L;
      bh[nt] = *reinterpret_cast<const f16x8*>(&SS[2][nl * 32 + gs]);
      bl[nt] = *reinterpret_cast<const f16x8*>(&SS[3][nl * 32 + gs]);
    }
#pragma unroll
    for (int mt = 0; mt < 4; ++mt) {
      const int ml = 64 * wm + 16 * mt + L;
      const f16x8 ah = *reinterpret_cast<const f16x8*>(&SS[0][ml * 32 + gs]);
      const f16x8 al = *reinterpret_cast<const f16x8*>(&SS[1][ml * 32 + gs]);
#pragma unroll
      for (int nt = 0; nt < 4; ++nt) {
        acc[mt][nt] =
            __builtin_amdgcn_mfma_f32_16x16x32_f16(al, bh[nt], acc[mt][nt], 0, 0, 0);
        acc[mt][nt] =
            __builtin_amdgcn_mfma_f32_16x16x32_f16(ah, bl[nt], acc[mt][nt], 0, 0, 0);
        acc[mt][nt] =
            __builtin_amdgcn_mfma_f32_16x16x32_f16(ah, bh[nt], acc[mt][nt], 0, 0, 0);
      }
    }
  }

  // epilogue: +bias, round to f16, store [B,H,S,D]
#pragma unroll
  for (int nt = 0; nt < 4; ++nt) {
    const int nmat = n0m + 64 * wn + 16 * nt + L;
    const float bval = bias[nmat];
    const int h_ = nmat >> 6, d_ = nmat & 63;
#pragma unroll
    for (int mt = 0; mt < 4; ++mt) {
#pragma unroll
      for (int j = 0; j < 4; ++j) {
        const int m = m0 + 64 * wm + 16 * mt + 4 * g + j;
        const int b_ = m >> 11, s_ = m & (NS - 1);
        dst[(((size_t)b_ * NH + h_) * NS + s_) * ND + d_] =
            __float2half(acc[mt][nt][j] + bval);
      }
    }
  }
}

// ---------------------------------------------------------------- attention
// MFMA flash attention (r3 structure), f16 F1/F2/P scratch + f16 q/k/v in:
// LDS 77.3 -> 52.75 KB -> 3 wg/CU.
__launch_bounds__(256, 3)
__global__ void attn_mfma(const __half* __restrict__ q,   // [B,H,S,D] f16
                          const __half* __restrict__ k,   // [B,H,S,D] f16
                          const __half* __restrict__ v,   // [B,H,S,D] f16
                          const float* __restrict__ E,    // [4095, 64] f32
                          const float* __restrict__ mask, // [B*S]
                          float* __restrict__ out) {      // [B,S,DM]
  __shared__ __align__(16) __half Qs[64 * 64];   //  8 KB, swizzled [l][d]
  __shared__ __align__(16) __half Ks[32 * 64];   //  4 KB, swizzled [r][d]
  __shared__ __align__(16) __half Es[96 * 64];   // 12 KB, swizzled [dloc][d]
  __shared__ __align__(16) __half Vt[64 * 40];   //  5 KB, [d][r] pad 40
  __shared__ __half F1s[64 * 100];               // 12.5 KB [ll][dloc]
  __shared__ __half F2s[32 * 100];               // 6.25 KB [rl][dloc]
  __shared__ __align__(16) __half Ps[64 * 40];   //  5 KB [ll][rl] pad 40

  const int t    = threadIdx.x;
  const int lane = t & 63;
  const int w    = t >> 6;     // wave 0..3, owns l-rows [16w,16w+16)
  const int g    = lane >> 4;  // lane group 0..3
  const int L    = lane & 15;
  const int l0   = blockIdx.x * 64;
  const int bh   = blockIdx.y;
  const int b    = bh / NH;
  const int h    = bh - b * NH;

  const __half* qp = q + ((size_t)bh * NS + l0) * ND;
  const __half* kp = k + (size_t)bh * NS * ND;
  const __half* vp = v + (size_t)bh * NS * ND;
  const float* mp = mask + (size_t)b * NS;

  // ---- stage Q once: f16 copy, row-swizzled (16B block ^= row&7)
#pragma unroll
  for (int s = 0; s < 4; ++s) {
    const int tau = t + 256 * s;
    const int r = tau >> 4, qd = tau & 15;
    const uint2 val =
        *reinterpret_cast<const uint2*>(&qp[(size_t)r * ND + qd * 4]);
    const int idx = r * 64 + ((((qd >> 1) ^ (r & 7)) << 3) | ((qd & 1) << 2));
    *reinterpret_cast<uint2*>(&Qs[idx]) = val;
  }

  f32x4 Oacc[4];
  float m_run[4], l_run[4];
#pragma unroll
  for (int j = 0; j < 4; ++j) { m_run[j] = -1e30f; l_run[j] = 0.f; }
#pragma unroll
  for (int nt = 0; nt < 4; ++nt) Oacc[nt] = {0.f, 0.f, 0.f, 0.f};

  const int rtw    = w >> 1;        // F2 row-tile owned by this wave
  const int dtbase = (w & 1) * 3;   // F2 d-tiles owned: dtbase..dtbase+2
  const int swL    = L & 7;
  const f32x4 Z = {0.f, 0.f, 0.f, 0.f};

  for (int r0 = 0; r0 < NS; r0 += 32) {
    __syncthreads();  // prev PV reads done before restage

    // ---- stage K (f16 swizzled copy)
#pragma unroll
    for (int s = 0; s < 2; ++s) {
      const int tau = t + 256 * s;
      const int r = tau >> 4, qd = tau & 15;
      const uint2 val = *reinterpret_cast<const uint2*>(
          &kp[(size_t)(r0 + r) * ND + qd * 4]);
      const int idx =
          r * 64 + ((((qd >> 1) ^ (r & 7)) << 3) | ((qd & 1) << 2));
      *reinterpret_cast<uint2*>(&Ks[idx]) = val;
    }
    // ---- stage V transposed [d][r]
#pragma unroll
    for (int s = 0; s < 2; ++s) {
      const int tau = t + 256 * s;
      const int rr = tau & 31, qd = tau >> 5;
      union { uint2 u; __half h[4]; } x;
      x.u = *reinterpret_cast<const uint2*>(
          &vp[(size_t)(r0 + rr) * ND + qd * 4]);
      Vt[(qd * 4 + 0) * 40 + rr] = x.h[0];
      Vt[(qd * 4 + 1) * 40 + rr] = x.h[1];
      Vt[(qd * 4 + 2) * 40 + rr] = x.h[2];
      Vt[(qd * 4 + 3) * 40 + rr] = x.h[3];
    }
    // ---- stage E window rows 0..95 (f32 -> f16, swizzled)
    const int start = l0 - r0 + 2016;  // = l0-r0+2047-31
#pragma unroll
    for (int s = 0; s < 3; ++s) {
      const int tau = t + 256 * s;
      const int row = tau >> 3, blk = tau & 7;
      int grow = start + row;
      grow = grow > 4094 ? 4094 : grow;  // row 95 pad, never gathered
      const float* ep = &E[(size_t)grow * ND + blk * 8];
      const float4 a = *reinterpret_cast<const float4*>(ep);
      const float4 c = *reinterpret_cast<const float4*>(ep + 4);
      union { __half2 h2[4]; uint4 u; } pk;
      pk.h2[0] = __floats2half2_rn(a.x, a.y);
      pk.h2[1] = __floats2half2_rn(a.z, a.w);
      pk.h2[2] = __floats2half2_rn(c.x, c.y);
      pk.h2[3] = __floats2half2_rn(c.z, c.w);
      *reinterpret_cast<uint4*>(&Es[row * 64 + ((blk ^ (row & 7)) << 3)]) =
          pk.u;
    }
    __syncthreads();

    // ---- operand fragments (b128, conflict-free via swizzle)
    const int rq = 16 * w + L;
    const f16x8 aQ0 = *reinterpret_cast<const f16x8*>(
        &Qs[rq * 64 + ((g ^ swL) << 3)]);
    const f16x8 aQ1 = *reinterpret_cast<const f16x8*>(
        &Qs[rq * 64 + (((4 + g) ^ swL) << 3)]);
    const f16x8 bK00 = *reinterpret_cast<const f16x8*>(
        &Ks[L * 64 + ((g ^ swL) << 3)]);
    const f16x8 bK01 = *reinterpret_cast<const f16x8*>(
        &Ks[L * 64 + (((4 + g) ^ swL) << 3)]);
    const f16x8 bK10 = *reinterpret_cast<const f16x8*>(
        &Ks[(16 + L) * 64 + ((g ^ swL) << 3)]);
    const f16x8 bK11 = *reinterpret_cast<const f16x8*>(
        &Ks[(16 + L) * 64 + (((4 + g) ^ swL) << 3)]);

    // S0 = Q.K^T
    f32x4 c0 = Z, c1 = Z;
    c0 = __builtin_amdgcn_mfma_f32_16x16x32_f16(aQ0, bK00, c0, 0, 0, 0);
    c0 = __builtin_amdgcn_mfma_f32_16x16x32_f16(aQ1, bK01, c0, 0, 0, 0);
    c1 = __builtin_amdgcn_mfma_f32_16x16x32_f16(aQ0, bK10, c1, 0, 0, 0);
    c1 = __builtin_amdgcn_mfma_f32_16x16x32_f16(aQ1, bK11, c1, 0, 0, 0);

    // F1 = Q.Ew^T
    f32x4 f1acc[6];
#pragma unroll
    for (int dt = 0; dt < 6; ++dt) {
      const int re = 16 * dt + L;
      const f16x8 be0 = *reinterpret_cast<const f16x8*>(
          &Es[re * 64 + ((g ^ swL) << 3)]);
      const f16x8 be1 = *reinterpret_cast<const f16x8*>(
          &Es[re * 64 + (((4 + g) ^ swL) << 3)]);
      f32x4 acc = Z;
      acc = __builtin_amdgcn_mfma_f32_16x16x32_f16(aQ0, be0, acc, 0, 0, 0);
      acc = __builtin_amdgcn_mfma_f32_16x16x32_f16(aQ1, be1, acc, 0, 0, 0);
      f1acc[dt] = acc;
    }
    // F2 = K.Ew^T (wave's (rtw, dtbase..+2) share)
    const f16x8 aK0 = rtw ? bK10 : bK00;
    const f16x8 aK1 = rtw ? bK11 : bK01;
    f32x4 f2acc[3];
#pragma unroll
    for (int m = 0; m < 3; ++m) {
      const int re = 16 * (dtbase + m) + L;
      const f16x8 be0 = *reinterpret_cast<const f16x8*>(
          &Es[re * 64 + ((g ^ swL) << 3)]);
      const f16x8 be1 = *reinterpret_cast<const f16x8*>(
          &Es[re * 64 + (((4 + g) ^ swL) << 3)]);
      f32x4 acc = Z;
      acc = __builtin_amdgcn_mfma_f32_16x16x32_f16(aK0, be0, acc, 0, 0, 0);
      acc = __builtin_amdgcn_mfma_f32_16x16x32_f16(aK1, be1, acc, 0, 0, 0);
      f2acc[m] = acc;
    }

    // ---- write F1, F2 as f16 (u16 stores; g-groups cover all 32 banks)
#pragma unroll
    for (int dt = 0; dt < 6; ++dt)
#pragma unroll
      for (int j = 0; j < 4; ++j)
        F1s[(16 * w + 4 * g + j) * 100 + 16 * dt + L] =
            __float2half(f1acc[dt][j]);
#pragma unroll
    for (int m = 0; m < 3; ++m)
#pragma unroll
      for (int j = 0; j < 4; ++j)
        F2s[(16 * rtw + 4 * g + j) * 100 + 16 * (dtbase + m) + L] =
            __float2half(f2acc[m][j]);
    __syncthreads();

    // ---- assemble scores + diagonal gather + online softmax
    float sc2[2][4];
    const float mk0 = mp[r0 + L];
    const float mk1 = mp[r0 + 16 + L];
#pragma unroll
    for (int j = 0; j < 4; ++j) {
      const int ll = 16 * w + 4 * g + j;
      {
        const int dl = ll - L + 31;
        sc2[0][j] = (c0[j] + __half2float(F1s[ll * 100 + dl]) +
                     __half2float(F2s[L * 100 + dl])) * 0.125f + mk0;
      }
      {
        const int rl = 16 + L;
        const int dl = ll - rl + 31;
        sc2[1][j] = (c1[j] + __half2float(F1s[ll * 100 + dl]) +
                     __half2float(F2s[rl * 100 + dl])) * 0.125f + mk1;
      }
    }
    float al[4];
#pragma unroll
    for (int j = 0; j < 4; ++j) {
      float mx = fmaxf(sc2[0][j], sc2[1][j]);
      mx = fmaxf(mx, __shfl_xor(mx, 1));
      mx = fmaxf(mx, __shfl_xor(mx, 2));
      mx = fmaxf(mx, __shfl_xor(mx, 4));
      mx = fmaxf(mx, __shfl_xor(mx, 8));
      const float mnew = fmaxf(m_run[j], mx);
      al[j] = __expf(m_run[j] - mnew);
      m_run[j] = mnew;
      const float p0 = __expf(sc2[0][j] - mnew);
      const float p1 = __expf(sc2[1][j] - mnew);
      sc2[0][j] = p0;
      sc2[1][j] = p1;
      float ps = p0 + p1;
      ps += __shfl_xor(ps, 1);
      ps += __shfl_xor(ps, 2);
      ps += __shfl_xor(ps, 4);
      ps += __shfl_xor(ps, 8);
      l_run[j] = l_run[j] * al[j] + ps;
    }
#pragma unroll
    for (int nt = 0; nt < 4; ++nt)
#pragma unroll
      for (int j = 0; j < 4; ++j) Oacc[nt][j] *= al[j];
#pragma unroll
    for (int j = 0; j < 4; ++j) {
      Ps[(16 * w + 4 * g + j) * 40 + L]      = __float2half(sc2[0][j]);
      Ps[(16 * w + 4 * g + j) * 40 + 16 + L] = __float2half(sc2[1][j]);
    }
    __syncthreads();

    // ---- PV: O += P.V (P read as f16x8 directly — no cvt)
    {
      const f16x8 aP =
          *reinterpret_cast<const f16x8*>(&Ps[(16 * w + L) * 40 + 8 * g]);
#pragma unroll
      for (int nt = 0; nt < 4; ++nt) {
        const f16x8 bV = *reinterpret_cast<const f16x8*>(
            &Vt[(16 * nt + L) * 40 + 8 * g]);
        Oacc[nt] = __builtin_amdgcn_mfma_f32_16x16x32_f16(aP, bV, Oacc[nt],
                                                          0, 0, 0);
      }
    }
  }

  // ---- epilogue: normalize, store [B,S,DM] f32
#pragma unroll
  for (int j = 0; j < 4; ++j) {
    const float inv = 1.0f / l_run[j];
    const int row = l0 + 16 * w + 4 * g + j;
    float* op = &out[((size_t)b * NS + row) * NDM + h * ND + L];
    op[0]  = Oacc[0][j] * inv;
    op[16] = Oacc[1][j] * inv;
    op[32] = Oacc[2][j] * inv;
    op[48] = Oacc[3][j] * inv;
  }
}

extern "C" void kernel_launch(void* const* d_in, const int* in_sizes, int n_in,
                              void* d_out, int out_size, void* d_ws, size_t ws_size,
                              hipStream_t stream) {
  const float* hs  = (const float*)d_in[0];
  const float* msk = (const float*)d_in[1];
  const float* Wq  = (const float*)d_in[2];
  const float* bq  = (const float*)d_in[3];
  const float* Wk  = (const float*)d_in[4];
  const float* bk  = (const float*)d_in[5];
  const float* Wv  = (const float*)d_in[6];
  const float* bv  = (const float*)d_in[7];
  const float* Ept = (const float*)d_in[8];
  float* out = (float*)d_out;

  const size_t per  = (size_t)NB * NH * NS * ND;  // 3,145,728
  const size_t wsz  = (size_t)NDM * NDM;          // 589,824
  __half* qb  = (__half*)d_ws;
  __half* kb  = qb + per;
  __half* vb  = kb + per;
  __half* Xh  = vb + per;
  __half* Xl  = Xh + per;          // X has same elem count as q/k/v
  __half* WhT = Xl + per;
  __half* WlT = WhT + 3 * wsz;
  // total ws: (5*per + 6*wsz)*2B = 38.5 MB

  cvt_split<<<dim3((int)(per / 4 / 256)), 256, 0, stream>>>(hs, Xh, Xl);
  cvt_w_t<<<dim3(12, 12, 3), 256, 0, stream>>>(Wq, Wk, Wv, WhT, WlT);
  qkv_mfma<<<dim3(18, 32), 256, 0, stream>>>(Xh, Xl, WhT, WlT, bq, bk, bv,
                                             qb, kb, vb);
  attn_mfma<<<dim3(NS / 64, NB * NH), 256, 0, stream>>>(qb, kb, vb, Ept,
                                                        msk, out);
}

// Round 6
// 531.770 us; speedup vs baseline: 2.6902x; 1.1979x over previous
//
#include <hip/hip_runtime.h>
#include <hip/hip_fp16.h>

#define NB 2
#define NS 2048
#define NDM 768
#define NH 12
#define ND 64
// dist_emb rows = 2*NS - 1 = 4095

typedef __attribute__((ext_vector_type(8))) _Float16 f16x8;
typedef __attribute__((ext_vector_type(4))) float f32x4;

// swizzle for [row][32-half] GEMM tiles: 16B-block idx XOR
__device__ __forceinline__ int swz(int row) {
  return (row & 3) ^ ((row >> 2) & 3);
}

// ------------------------------------------------------- split-f16 converts
__launch_bounds__(256)
__global__ void cvt_split(const float* __restrict__ x, __half* __restrict__ xh,
                          __half* __restrict__ xl) {
  const int i = blockIdx.x * 256 + threadIdx.x;  // one float4
  const float4 v = reinterpret_cast<const float4*>(x)[i];
  const float a[4] = {v.x, v.y, v.z, v.w};
  union { __half h[4]; uint2 u; } ph, pl;
#pragma unroll
  for (int j = 0; j < 4; ++j) {
    ph.h[j] = __float2half(a[j]);
    pl.h[j] = __float2half(a[j] - __half2float(ph.h[j]));
  }
  *reinterpret_cast<uint2*>(&xh[(size_t)i * 4]) = ph.u;
  *reinterpret_cast<uint2*>(&xl[(size_t)i * 4]) = pl.u;
}

__launch_bounds__(256)
__global__ void cvt_w_t(const float* __restrict__ Wq,
                        const float* __restrict__ Wk,
                        const float* __restrict__ Wv,
                        __half* __restrict__ WhT, __half* __restrict__ WlT) {
  __shared__ float Tf[64][65];
  const int t = threadIdx.x;
  const int k0 = blockIdx.x * 64;
  const int n0 = blockIdx.y * 64;
  const int z = blockIdx.z;
  const float* W = z == 0 ? Wq : (z == 1 ? Wk : Wv);
  __half* wh = WhT + (size_t)z * NDM * NDM;
  __half* wl = WlT + (size_t)z * NDM * NDM;
#pragma unroll
  for (int s = 0; s < 4; ++s) {
    const int lin = t + 256 * s;
    const int r = lin >> 4, c4 = (lin & 15) * 4;
    const float4 v = *reinterpret_cast<const float4*>(
        &W[(size_t)(k0 + r) * NDM + n0 + c4]);
    Tf[r][c4 + 0] = v.x;
    Tf[r][c4 + 1] = v.y;
    Tf[r][c4 + 2] = v.z;
    Tf[r][c4 + 3] = v.w;
  }
  __syncthreads();
#pragma unroll
  for (int s = 0; s < 4; ++s) {
    const int lin = t + 256 * s;
    const int nl = lin >> 4, k4 = (lin & 15) * 4;
    union { __half h[4]; uint2 u; } ph, pl;
#pragma unroll
    for (int i = 0; i < 4; ++i) {
      const float f = Tf[k4 + i][nl];
      ph.h[i] = __float2half(f);
      pl.h[i] = __float2half(f - __half2float(ph.h[i]));
    }
    *reinterpret_cast<uint2*>(&wh[(size_t)(n0 + nl) * NDM + k0 + k4]) = ph.u;
    *reinterpret_cast<uint2*>(&wl[(size_t)(n0 + nl) * NDM + k0 + k4]) = pl.u;
  }
}

// ---------------------------------------------------------------- QKV GEMM
// (unchanged from round 5 — split-f16 MFMA, passing)
__launch_bounds__(256, 2)
__global__ void qkv_mfma(const __half* __restrict__ Xh,
                         const __half* __restrict__ Xl,
                         const __half* __restrict__ WhT,  // [3][768n][768k]
                         const __half* __restrict__ WlT,
                         const float* __restrict__ bq,
                         const float* __restrict__ bk,
                         const float* __restrict__ bv,
                         __half* __restrict__ qb, __half* __restrict__ kb,
                         __half* __restrict__ vb) {
  __shared__ __align__(16) __half SS[4][128 * 32];  // Ah, Al, Bh, Bl

  const int t = threadIdx.x;
  const int lane = t & 63;
  const int w = t >> 6;
  const int g = lane >> 4;
  const int L = lane & 15;
  const int wm = w & 1, wn = w >> 1;
  const int widx = blockIdx.x / 6;
  const int n0m = (blockIdx.x % 6) * 128;
  const int m0 = blockIdx.y * 128;

  const __half* wh = WhT + (size_t)widx * NDM * NDM;
  const __half* wl = WlT + (size_t)widx * NDM * NDM;
  const float* bias = widx == 0 ? bq : (widx == 1 ? bk : bv);
  __half* dst = widx == 0 ? qb : (widx == 1 ? kb : vb);

  const __half* srcs[4] = {Xh + (size_t)m0 * NDM, Xl + (size_t)m0 * NDM,
                           wh + (size_t)n0m * NDM, wl + (size_t)n0m * NDM};

  uint4 rv[8];
#pragma unroll
  for (int u = 0; u < 8; ++u) {
    const int slot = t + 256 * u;
    const int bsel = slot >> 9, within = slot & 511;
    const int row = within >> 2, blk = within & 3;
    rv[u] = *reinterpret_cast<const uint4*>(srcs[bsel] + (size_t)row * NDM +
                                            blk * 8);
  }

  f32x4 acc[4][4];
#pragma unroll
  for (int mt = 0; mt < 4; ++mt)
#pragma unroll
    for (int nt = 0; nt < 4; ++nt) acc[mt][nt] = {0.f, 0.f, 0.f, 0.f};

  const int sL = (L & 3) ^ ((L >> 2) & 3);
  const int gs = (g ^ sL) << 3;

  for (int kt = 0; kt < 24; ++kt) {
    __syncthreads();
#pragma unroll
    for (int u = 0; u < 8; ++u) {
      const int slot = t + 256 * u;
      const int bsel = slot >> 9, within = slot & 511;
      const int row = within >> 2, blk = within & 3;
      *reinterpret_cast<uint4*>(&SS[bsel][row * 32 + ((blk ^ swz(row)) << 3)]) =
          rv[u];
    }
    if (kt < 23) {
      const int k0 = (kt + 1) * 32;
#pragma unroll
      for (int u = 0; u < 8; ++u) {
        const int slot = t + 256 * u;
        const int bsel = slot >> 9, within = slot & 511;
        const int row = within >> 2, blk = within & 3;
        rv[u] = *reinterpret_cast<const uint4*>(
            srcs[bsel] + (size_t)row * NDM + k0 + blk * 8);
      }
    }
    __syncthreads();

    f16x8 bh[4], bl[4];
#pragma unroll
    for (int nt = 0; nt < 4; ++nt) {
      const int nl = 64 * wn + 16 * nt + L;
      bh[nt] = *reinterpret_cast<const f16x8*>(&SS[2][nl * 32 + gs]);
      bl[nt] = *reinterpret_cast<const f16x8*>(&SS[3][nl * 32 + gs]);
    }
#pragma unroll
    for (int mt = 0; mt < 4; ++mt) {
      const int ml = 64 * wm + 16 * mt + L;
      const f16x8 ah = *reinterpret_cast<const f16x8*>(&SS[0][ml * 32 + gs]);
      const f16x8 al = *reinterpret_cast<const f16x8*>(&SS[1][ml * 32 + gs]);
#pragma unroll
      for (int nt = 0; nt < 4; ++nt) {
        acc[mt][nt] =
            __builtin_amdgcn_mfma_f32_16x16x32_f16(al, bh[nt], acc[mt][nt], 0, 0, 0);
        acc[mt][nt] =
            __builtin_amdgcn_mfma_f32_16x16x32_f16(ah, bl[nt], acc[mt][nt], 0, 0, 0);
        acc[mt][nt] =
            __builtin_amdgcn_mfma_f32_16x16x32_f16(ah, bh[nt], acc[mt][nt], 0, 0, 0);
      }
    }
  }

#pragma unroll
  for (int nt = 0; nt < 4; ++nt) {
    const int nmat = n0m + 64 * wn + 16 * nt + L;
    const float bval = bias[nmat];
    const int h_ = nmat >> 6, d_ = nmat & 63;
#pragma unroll
    for (int mt = 0; mt < 4; ++mt) {
#pragma unroll
      for (int j = 0; j < 4; ++j) {
        const int m = m0 + 64 * wm + 16 * mt + 4 * g + j;
        const int b_ = m >> 11, s_ = m & (NS - 1);
        dst[(((size_t)b_ * NH + h_) * NS + s_) * ND + d_] =
            __float2half(acc[mt][nt][j] + bval);
      }
    }
  }
}

// ---------------------------------------------------------------- attention
// MFMA flash attn v2: QBLK=64, KVBLK=64 (32 iters, 4 barriers/iter — half of
// r5's per-kv-element barrier count), T14 async prefetch (next K/V/E issued
// before the MFMA phase), T5 setprio, circular E window (stage 64 new rows
// per iter), P aliased onto Ks (union). LDS 75 KB -> 2 wg/CU.
__launch_bounds__(256, 2)
__global__ void attn_mfma(const __half* __restrict__ q,   // [B,H,S,D] f16
                          const __half* __restrict__ k,   // [B,H,S,D] f16
                          const __half* __restrict__ v,   // [B,H,S,D] f16
                          const float* __restrict__ E,    // [4095, 64] f32
                          const float* __restrict__ mask, // [B*S]
                          float* __restrict__ out) {      // [B,S,DM]
  struct __align__(16) SMem {
    __half Qs[64 * 64];                                  //  8 KB swizzled
    union { __half Ks[64 * 64]; __half Ps[64 * 72]; } kp; // 9 KB (K then P)
    __half Es[128 * 64];                                 // 16 KB circular
    __half Vt[64 * 72];                                  //  9 KB [d][r]
    __half F1[64 * 132];                                 // 16.5 KB [ll][dl]
    __half F2[64 * 132];                                 // 16.5 KB [rl][dl]
  };
  __shared__ SMem sm;

  const int t    = threadIdx.x;
  const int lane = t & 63;
  const int w    = t >> 6;     // wave 0..3, owns l-rows [16w,16w+16)
  const int g    = lane >> 4;
  const int L    = lane & 15;
  const int sw   = L & 7;
  const int l0   = blockIdx.x * 64;
  const int bh   = blockIdx.y;
  const int b    = bh / NH;
  const int h    = bh - b * NH;

  const __half* qp  = q + ((size_t)bh * NS + l0) * ND;
  const __half* kpg = k + (size_t)bh * NS * ND;
  const __half* vpg = v + (size_t)bh * NS * ND;
  const float*  mp  = mask + (size_t)b * NS;

  // ---- prologue: stage Q, K(it0), V(it0), E window it0 (dl 0..127)
#pragma unroll
  for (int s = 0; s < 4; ++s) {
    const int tau = t + 256 * s;
    const int r = tau >> 4, qd = tau & 15;
    const int idx = r * 64 + ((((qd >> 1) ^ (r & 7)) << 3) | ((qd & 1) << 2));
    sm.Qs[0] = sm.Qs[0];  // no-op
    *reinterpret_cast<uint2*>(&sm.Qs[idx]) =
        *reinterpret_cast<const uint2*>(&qp[(size_t)r * ND + qd * 4]);
    *reinterpret_cast<uint2*>(&sm.kp.Ks[idx]) =
        *reinterpret_cast<const uint2*>(&kpg[(size_t)r * ND + qd * 4]);
  }
#pragma unroll
  for (int s = 0; s < 4; ++s) {
    const int tau = t + 256 * s;
    const int rr = tau & 63, qd = tau >> 6;  // qd 0..15
    union { uint2 u; __half hh[4]; } x;
    x.u = *reinterpret_cast<const uint2*>(&vpg[(size_t)rr * ND + qd * 4]);
#pragma unroll
    for (int c = 0; c < 4; ++c) sm.Vt[(qd * 4 + c) * 72 + rr] = x.hh[c];
  }
  {
    const int start0 = l0 + 1984;
#pragma unroll
    for (int s = 0; s < 4; ++s) {
      const int tau = t + 256 * s;
      const int row = tau >> 3, blk = tau & 7;  // row 0..127
      int grow = start0 + row;
      grow = grow > 4094 ? 4094 : grow;
      const float* ep = &E[(size_t)grow * ND + blk * 8];
      const float4 a = *reinterpret_cast<const float4*>(ep);
      const float4 c = *reinterpret_cast<const float4*>(ep + 4);
      union { __half2 h2[4]; uint4 u; } pk;
      pk.h2[0] = __floats2half2_rn(a.x, a.y);
      pk.h2[1] = __floats2half2_rn(a.z, a.w);
      pk.h2[2] = __floats2half2_rn(c.x, c.y);
      pk.h2[3] = __floats2half2_rn(c.z, c.w);
      *reinterpret_cast<uint4*>(&sm.Es[row * 64 + ((blk ^ (row & 7)) << 3)]) =
          pk.u;
    }
  }
  __syncthreads();

  // persistent Q fragments (Qs never overwritten)
  const int rq = 16 * w + L;
  const f16x8 aQ0 =
      *reinterpret_cast<const f16x8*>(&sm.Qs[rq * 64 + ((g ^ sw) << 3)]);
  const f16x8 aQ1 =
      *reinterpret_cast<const f16x8*>(&sm.Qs[rq * 64 + (((4 + g) ^ sw) << 3)]);

  f32x4 Oacc[4];
  float m_run[4], l_run[4];
#pragma unroll
  for (int j = 0; j < 4; ++j) { m_run[j] = -1e30f; l_run[j] = 0.f; }
#pragma unroll
  for (int nt = 0; nt < 4; ++nt) Oacc[nt] = {0.f, 0.f, 0.f, 0.f};

  const f32x4 Z = {0.f, 0.f, 0.f, 0.f};

  for (int it = 0; it < 32; ++it) {
    const int r0 = it * 64;
    const int off = (it & 1) * 64;  // E circular offset for THIS iter

    // ---- T14: issue next-iter global loads (drain at B2, hidden by MFMA)
    uint2 kr[4], vr[4];
    float4 er[4];
    const bool pf = it < 31;
    if (pf) {
      const int r0n = r0 + 64;
#pragma unroll
      for (int s = 0; s < 4; ++s) {
        const int tau = t + 256 * s;
        kr[s] = *reinterpret_cast<const uint2*>(
            &kpg[(size_t)(r0n + (tau >> 4)) * ND + (tau & 15) * 4]);
        vr[s] = *reinterpret_cast<const uint2*>(
            &vpg[(size_t)(r0n + (tau & 63)) * ND + (tau >> 6) * 4]);
      }
      const int startn = l0 + 1984 - 64 * (it + 1);
#pragma unroll
      for (int s = 0; s < 2; ++s) {
        const int tau = t + 256 * s;
        const int row = tau >> 3, blk = tau & 7;  // row 0..63, in-range
        const float* ep = &E[(size_t)(startn + row) * ND + blk * 8];
        er[2 * s]     = *reinterpret_cast<const float4*>(ep);
        er[2 * s + 1] = *reinterpret_cast<const float4*>(ep + 4);
      }
    }
    float mk[4];
#pragma unroll
    for (int rt = 0; rt < 4; ++rt) mk[rt] = mp[r0 + 16 * rt + L];

    // ---- MFMA phase: QK^T, F1 = Q.Ew^T, F2 = K.Ew^T
    __builtin_amdgcn_s_setprio(1);
    f16x8 bKa[4], bKb[4];
#pragma unroll
    for (int rt = 0; rt < 4; ++rt) {
      const int rl = 16 * rt + L;
      bKa[rt] = *reinterpret_cast<const f16x8*>(
          &sm.kp.Ks[rl * 64 + ((g ^ sw) << 3)]);
      bKb[rt] = *reinterpret_cast<const f16x8*>(
          &sm.kp.Ks[rl * 64 + (((4 + g) ^ sw) << 3)]);
    }
    f32x4 c[4];
#pragma unroll
    for (int rt = 0; rt < 4; ++rt) {
      f32x4 acc = Z;
      acc = __builtin_amdgcn_mfma_f32_16x16x32_f16(aQ0, bKa[rt], acc, 0, 0, 0);
      acc = __builtin_amdgcn_mfma_f32_16x16x32_f16(aQ1, bKb[rt], acc, 0, 0, 0);
      c[rt] = acc;
    }
    // F2 A-operand: K rows [16w,16w+16) — re-read (avoid runtime-indexed regs)
    const f16x8 aK0 = *reinterpret_cast<const f16x8*>(
        &sm.kp.Ks[(16 * w + L) * 64 + ((g ^ sw) << 3)]);
    const f16x8 aK1 = *reinterpret_cast<const f16x8*>(
        &sm.kp.Ks[(16 * w + L) * 64 + (((4 + g) ^ sw) << 3)]);
#pragma unroll
    for (int dt = 0; dt < 8; ++dt) {
      const int phys = ((16 * dt + L) + off) & 127;
      const f16x8 be0 = *reinterpret_cast<const f16x8*>(
          &sm.Es[phys * 64 + ((g ^ sw) << 3)]);
      const f16x8 be1 = *reinterpret_cast<const f16x8*>(
          &sm.Es[phys * 64 + (((4 + g) ^ sw) << 3)]);
      f32x4 f1 = Z, f2 = Z;
      f1 = __builtin_amdgcn_mfma_f32_16x16x32_f16(aQ0, be0, f1, 0, 0, 0);
      f1 = __builtin_amdgcn_mfma_f32_16x16x32_f16(aQ1, be1, f1, 0, 0, 0);
      f2 = __builtin_amdgcn_mfma_f32_16x16x32_f16(aK0, be0, f2, 0, 0, 0);
      f2 = __builtin_amdgcn_mfma_f32_16x16x32_f16(aK1, be1, f2, 0, 0, 0);
#pragma unroll
      for (int j = 0; j < 4; ++j) {
        const int rowi = 16 * w + 4 * g + j;
        sm.F1[rowi * 132 + 16 * dt + L] = __float2half(f1[j]);
        sm.F2[rowi * 132 + 16 * dt + L] = __float2half(f2[j]);
      }
    }
    __builtin_amdgcn_s_setprio(0);
    __syncthreads();  // B2: F1/F2 visible (K frag reads all done)

    // ---- gather + online softmax
    float sc[4][4];  // [j][rt]
#pragma unroll
    for (int j = 0; j < 4; ++j) {
      const int ll = 16 * w + 4 * g + j;
#pragma unroll
      for (int rt = 0; rt < 4; ++rt) {
        const int rl = 16 * rt + L;
        const int dl = ll - rl + 63;
        sc[j][rt] = (c[rt][j] + __half2float(sm.F1[ll * 132 + dl]) +
                     __half2float(sm.F2[rl * 132 + dl])) * 0.125f + mk[rt];
      }
    }
    float al[4];
#pragma unroll
    for (int j = 0; j < 4; ++j) {
      float mx = fmaxf(fmaxf(sc[j][0], sc[j][1]), fmaxf(sc[j][2], sc[j][3]));
      mx = fmaxf(mx, __shfl_xor(mx, 1));
      mx = fmaxf(mx, __shfl_xor(mx, 2));
      mx = fmaxf(mx, __shfl_xor(mx, 4));
      mx = fmaxf(mx, __shfl_xor(mx, 8));
      const float mnew = fmaxf(m_run[j], mx);
      al[j] = __expf(m_run[j] - mnew);
      m_run[j] = mnew;
      float ps = 0.f;
#pragma unroll
      for (int rt = 0; rt < 4; ++rt) {
        const float p = __expf(sc[j][rt] - mnew);
        sc[j][rt] = p;
        ps += p;
      }
      ps += __shfl_xor(ps, 1);
      ps += __shfl_xor(ps, 2);
      ps += __shfl_xor(ps, 4);
      ps += __shfl_xor(ps, 8);
      l_run[j] = l_run[j] * al[j] + ps;
    }
#pragma unroll
    for (int nt = 0; nt < 4; ++nt)
#pragma unroll
      for (int j = 0; j < 4; ++j) Oacc[nt][j] *= al[j];
    // P write into the K/P union region (K reads finished before B2)
#pragma unroll
    for (int j = 0; j < 4; ++j) {
      const int ll = 16 * w + 4 * g + j;
#pragma unroll
      for (int rt = 0; rt < 4; ++rt)
        sm.kp.Ps[ll * 72 + 16 * rt + L] = __float2half(sc[j][rt]);
    }
    __syncthreads();  // B3: P visible

    // ---- PV: O += P.V  (K=64 -> 2 mfma per d-tile)
    __builtin_amdgcn_s_setprio(1);
    {
      const int pr = (16 * w + L) * 72;
      const f16x8 aP0 = *reinterpret_cast<const f16x8*>(&sm.kp.Ps[pr + 8 * g]);
      const f16x8 aP1 =
          *reinterpret_cast<const f16x8*>(&sm.kp.Ps[pr + 32 + 8 * g]);
#pragma unroll
      for (int nt = 0; nt < 4; ++nt) {
        const int vb_ = (16 * nt + L) * 72;
        const f16x8 bV0 =
            *reinterpret_cast<const f16x8*>(&sm.Vt[vb_ + 8 * g]);
        const f16x8 bV1 =
            *reinterpret_cast<const f16x8*>(&sm.Vt[vb_ + 32 + 8 * g]);
        Oacc[nt] =
            __builtin_amdgcn_mfma_f32_16x16x32_f16(aP0, bV0, Oacc[nt], 0, 0, 0);
        Oacc[nt] =
            __builtin_amdgcn_mfma_f32_16x16x32_f16(aP1, bV1, Oacc[nt], 0, 0, 0);
      }
    }
    __builtin_amdgcn_s_setprio(0);
    __syncthreads();  // B4: PV reads done (P-region/Vt/Es free to overwrite)

    // ---- stage prefetched K/V/E for it+1
    if (pf) {
#pragma unroll
      for (int s = 0; s < 4; ++s) {
        const int tau = t + 256 * s;
        const int r = tau >> 4, qd = tau & 15;
        const int idx =
            r * 64 + ((((qd >> 1) ^ (r & 7)) << 3) | ((qd & 1) << 2));
        *reinterpret_cast<uint2*>(&sm.kp.Ks[idx]) = kr[s];
      }
#pragma unroll
      for (int s = 0; s < 4; ++s) {
        const int tau = t + 256 * s;
        const int rr = tau & 63, qd = tau >> 6;
        union { uint2 u; __half hh[4]; } x;
        x.u = vr[s];
#pragma unroll
        for (int cc = 0; cc < 4; ++cc) sm.Vt[(qd * 4 + cc) * 72 + rr] = x.hh[cc];
      }
      const int offn = ((it + 1) & 1) * 64;
#pragma unroll
      for (int s = 0; s < 2; ++s) {
        const int tau = t + 256 * s;
        const int row = tau >> 3, blk = tau & 7;
        const int phys = (row + offn) & 127;
        const float4 a = er[2 * s];
        const float4 cc = er[2 * s + 1];
        union { __half2 h2[4]; uint4 u; } pk;
        pk.h2[0] = __floats2half2_rn(a.x, a.y);
        pk.h2[1] = __floats2half2_rn(a.z, a.w);
        pk.h2[2] = __floats2half2_rn(cc.x, cc.y);
        pk.h2[3] = __floats2half2_rn(cc.z, cc.w);
        *reinterpret_cast<uint4*>(
            &sm.Es[phys * 64 + ((blk ^ (phys & 7)) << 3)]) = pk.u;
      }
      __syncthreads();  // B1': staged tiles visible for next iter
    }
  }

  // ---- epilogue: normalize, store [B,S,DM] f32
#pragma unroll
  for (int j = 0; j < 4; ++j) {
    const float inv = 1.0f / l_run[j];
    const int row = l0 + 16 * w + 4 * g + j;
    float* op = &out[((size_t)b * NS + row) * NDM + h * ND + L];
    op[0]  = Oacc[0][j] * inv;
    op[16] = Oacc[1][j] * inv;
    op[32] = Oacc[2][j] * inv;
    op[48] = Oacc[3][j] * inv;
  }
}

extern "C" void kernel_launch(void* const* d_in, const int* in_sizes, int n_in,
                              void* d_out, int out_size, void* d_ws, size_t ws_size,
                              hipStream_t stream) {
  const float* hs  = (const float*)d_in[0];
  const float* msk = (const float*)d_in[1];
  const float* Wq  = (const float*)d_in[2];
  const float* bq  = (const float*)d_in[3];
  const float* Wk  = (const float*)d_in[4];
  const float* bk  = (const float*)d_in[5];
  const float* Wv  = (const float*)d_in[6];
  const float* bv  = (const float*)d_in[7];
  const float* Ept = (const float*)d_in[8];
  float* out = (float*)d_out;

  const size_t per = (size_t)NB * NH * NS * ND;  // 3,145,728
  const size_t wsz = (size_t)NDM * NDM;          // 589,824
  __half* qb  = (__half*)d_ws;
  __half* kb  = qb + per;
  __half* vb  = kb + per;
  __half* Xh  = vb + per;
  __half* Xl  = Xh + per;
  __half* WhT = Xl + per;
  __half* WlT = WhT + 3 * wsz;

  cvt_split<<<dim3((int)(per / 4 / 256)), 256, 0, stream>>>(hs, Xh, Xl);
  cvt_w_t<<<dim3(12, 12, 3), 256, 0, stream>>>(Wq, Wk, Wv, WhT, WlT);
  qkv_mfma<<<dim3(18, 32), 256, 0, stream>>>(Xh, Xl, WhT, WlT, bq, bk, bv,
                                             qb, kb, vb);
  attn_mfma<<<dim3(NS / 64, NB * NH), 256, 0, stream>>>(qb, kb, vb, Ept,
                                                        msk, out);
}